// Round 1
// 551.147 us; speedup vs baseline: 1.1605x; 1.1605x over previous
//
#include <hip/hip_runtime.h>

typedef __bf16 bf16x8 __attribute__((ext_vector_type(8)));
typedef __bf16 bf16x4 __attribute__((ext_vector_type(4)));
typedef float  f32x4  __attribute__((ext_vector_type(4)));

#define NTOK  49
#define CDIM  128
#define QK_SCALE 0.17677669529663687f   // 1/sqrt(32)

// workspace offsets (bytes)
#define WQKV_OFF  0          // 384*128 bf16 = 98304 B
#define WPROJ_OFF 98304      // 128*128 bf16 = 32768 B
#define BIASF_OFF 131072     // 4*49*49 f32  = 38416 B

// Uniform LDS XOR swizzle: granule (8 bf16 = 16 B) index's low 3 bits are
// XORed with (row & 7). All strides are multiples of 64 elements, so bank
// position is set purely by the swizzled granule -> fragment reads (16 lanes,
// consecutive rows, same column) spread over 8 distinct 16B slots = 2-way max.
__device__ __forceinline__ int swz(int row, int col) {
    return (col & ~63) | ((((col >> 3) ^ row) & 7) << 3) | (col & 7);
}

__global__ void prep_kernel(const float* __restrict__ qkv_w,
                            const float* __restrict__ proj_w,
                            const float* __restrict__ bias_table,
                            const int*   __restrict__ rel_index,
                            __bf16* __restrict__ wqkv,
                            __bf16* __restrict__ wproj,
                            float*  __restrict__ biasf) {
    int t = blockIdx.x * 256 + threadIdx.x;
    if (t < 384 * 128) wqkv[t]  = (__bf16)qkv_w[t];
    if (t < 128 * 128) wproj[t] = (__bf16)proj_w[t];
    if (t < 4 * 2401) {
        int h = t / 2401, ij = t % 2401;
        biasf[t] = bias_table[rel_index[ij] * 4 + h];   // bias_full[h][i][j]
    }
}

__launch_bounds__(256, 3)
__global__ void winattn_kernel(const float* __restrict__ x,
                               const float* __restrict__ mask,
                               const float* __restrict__ qkv_b,
                               const float* __restrict__ proj_b,
                               const __bf16* __restrict__ wqkv,
                               const __bf16* __restrict__ wproj,
                               const float* __restrict__ biasf,
                               float* __restrict__ out) {
    // bufA: x [64][128]  -> vt [128][64]   (aliased; both 16384 B)
    // bufB: q|k [64][256] -> p [256][64] -> O [64][128]  (aliased; 32768 B)
    __shared__ __bf16 lds_a[64 * 128];
    __shared__ __bf16 lds_b[64 * 256];

    const int tid  = threadIdx.x;
    const int w    = blockIdx.x;
    const int wave = tid >> 6;
    const int lane = tid & 63;
    const int quad = lane >> 4;
    const int l16  = lane & 15;

    // ---------------- phase 0: x (fp32) -> lds_a (bf16), rows>=49 zeroed ----
    {
        int row = tid >> 2;           // 0..63
        int c0  = (tid & 3) * 32;     // 0,32,64,96
        __align__(16) __bf16 tmp[32];
        if (row < NTOK) {
            const float4* src = (const float4*)(x + ((size_t)w * NTOK + row) * CDIM + c0);
            #pragma unroll
            for (int i = 0; i < 8; ++i) {
                float4 f = src[i];
                tmp[i*4+0] = (__bf16)f.x; tmp[i*4+1] = (__bf16)f.y;
                tmp[i*4+2] = (__bf16)f.z; tmp[i*4+3] = (__bf16)f.w;
            }
        } else {
            #pragma unroll
            for (int i = 0; i < 32; ++i) tmp[i] = (__bf16)0.0f;
        }
        #pragma unroll
        for (int i = 0; i < 4; ++i)
            *(bf16x8*)&lds_a[row * 128 + swz(row, c0 + i*8)] = *(bf16x8*)&tmp[i*8];
    }
    __syncthreads();

    // ---------------- phase 1: qkv = x @ Wqkv^T + b ------------------------
    // Tile map: q tiles (half*4+wave), k tiles (wave*2+half), v tiles (half*4+wave).
    // q,k -> lds_b; v held in registers (packed bf16x4) until x is dead.
    bf16x4 vreg[2][4];
    #pragma unroll
    for (int half = 0; half < 2; ++half) {
        const int oq = (half*4 + wave) * 16 + l16;         // 0..127
        const int ok = 128 + (wave*2 + half) * 16 + l16;   // 128..255
        const int ov = 256 + (half*4 + wave) * 16 + l16;   // 256..383
        f32x4 acc[3][4];
        #pragma unroll
        for (int a = 0; a < 3; ++a)
            #pragma unroll
            for (int b = 0; b < 4; ++b) acc[a][b] = (f32x4){0.f,0.f,0.f,0.f};

        #pragma unroll
        for (int kt = 0; kt < 4; ++kt) {
            bf16x8 a4[4];
            #pragma unroll
            for (int mt = 0; mt < 4; ++mt) {
                int rr = mt*16 + l16;
                a4[mt] = *(bf16x8*)&lds_a[rr * 128 + swz(rr, kt*32 + quad*8)];
            }
            bf16x8 bq = *(const bf16x8*)(wqkv + (size_t)oq * CDIM + kt*32 + quad*8);
            bf16x8 bk = *(const bf16x8*)(wqkv + (size_t)ok * CDIM + kt*32 + quad*8);
            bf16x8 bv = *(const bf16x8*)(wqkv + (size_t)ov * CDIM + kt*32 + quad*8);
            #pragma unroll
            for (int mt = 0; mt < 4; ++mt) {
                acc[0][mt] = __builtin_amdgcn_mfma_f32_16x16x32_bf16(a4[mt], bq, acc[0][mt], 0, 0, 0);
                acc[1][mt] = __builtin_amdgcn_mfma_f32_16x16x32_bf16(a4[mt], bk, acc[1][mt], 0, 0, 0);
                acc[2][mt] = __builtin_amdgcn_mfma_f32_16x16x32_bf16(a4[mt], bv, acc[2][mt], 0, 0, 0);
            }
        }
        float bqb = qkv_b[oq], bkb = qkv_b[ok], bvb = qkv_b[ov];
        #pragma unroll
        for (int mt = 0; mt < 4; ++mt) {
            #pragma unroll
            for (int r = 0; r < 4; ++r) {
                int row = mt*16 + quad*4 + r;
                lds_b[row*256 + swz(row, oq)] = (__bf16)((acc[0][mt][r] + bqb) * QK_SCALE);
                lds_b[row*256 + swz(row, ok)] = (__bf16)(acc[1][mt][r] + bkb);
            }
            bf16x4 vv;
            #pragma unroll
            for (int r = 0; r < 4; ++r) vv[r] = (__bf16)(acc[2][mt][r] + bvb);
            vreg[half][mt] = vv;
        }
    }
    __syncthreads();   // x reads done everywhere; q,k visible

    // v -> lds_a as vt[chan][token] (x is dead). 8B stores, 4 contig tokens.
    #pragma unroll
    for (int half = 0; half < 2; ++half) {
        int vc = (half*4 + wave) * 16 + l16;   // v channel 0..127
        #pragma unroll
        for (int mt = 0; mt < 4; ++mt) {
            int tok = mt*16 + quad*4;
            *(bf16x4*)&lds_a[vc * 64 + swz(vc, tok)] = vreg[half][mt];
        }
    }

    // ---------------- phase 2: S = q k^T + bias + mask; softmax ------------
    {
        const int h = wave;
        bf16x8 bk[4];
        #pragma unroll
        for (int nt = 0; nt < 4; ++nt) {
            int rr = nt*16 + l16;
            bk[nt] = *(bf16x8*)&lds_b[rr*256 + swz(rr, 128 + h*32 + quad*8)];
        }
        f32x4 s[4][4];
        #pragma unroll
        for (int mt = 0; mt < 4; ++mt) {
            int rr = mt*16 + l16;
            bf16x8 aq = *(bf16x8*)&lds_b[rr*256 + swz(rr, h*32 + quad*8)];
            #pragma unroll
            for (int nt = 0; nt < 4; ++nt) {
                f32x4 z = (f32x4){0.f,0.f,0.f,0.f};
                s[mt][nt] = __builtin_amdgcn_mfma_f32_16x16x32_bf16(aq, bk[nt], z, 0, 0, 0);
            }
        }

        const float* bh = biasf + h * 2401;
        const float* mh = mask + (size_t)(w & 63) * 2401;
        #pragma unroll
        for (int mt = 0; mt < 4; ++mt) {
            #pragma unroll
            for (int r = 0; r < 4; ++r) {
                int i = mt*16 + quad*4 + r;
                float v[4];
                #pragma unroll
                for (int nt = 0; nt < 4; ++nt) {
                    int j = nt*16 + l16;
                    float t = s[mt][nt][r];
                    if (j < NTOK) { if (i < NTOK) t += bh[i*49 + j] + mh[i*49 + j]; }
                    else t = -1e30f;
                    v[nt] = t;
                }
                float mx = fmaxf(fmaxf(v[0], v[1]), fmaxf(v[2], v[3]));
                mx = fmaxf(mx, __shfl_xor(mx, 1, 64));
                mx = fmaxf(mx, __shfl_xor(mx, 2, 64));
                mx = fmaxf(mx, __shfl_xor(mx, 4, 64));
                mx = fmaxf(mx, __shfl_xor(mx, 8, 64));
                float e[4], sum = 0.f;
                #pragma unroll
                for (int nt = 0; nt < 4; ++nt) { e[nt] = __expf(v[nt] - mx); sum += e[nt]; }
                sum += __shfl_xor(sum, 1, 64);
                sum += __shfl_xor(sum, 2, 64);
                sum += __shfl_xor(sum, 4, 64);
                sum += __shfl_xor(sum, 8, 64);
                float inv = 1.0f / sum;
                #pragma unroll
                for (int nt = 0; nt < 4; ++nt) s[mt][nt][r] = e[nt] * inv;
            }
        }
        __syncthreads();   // all waves done reading q,k before p overwrites lds_b
        #pragma unroll
        for (int mt = 0; mt < 4; ++mt)
            #pragma unroll
            for (int r = 0; r < 4; ++r) {
                int prow = (h << 6) + mt*16 + quad*4 + r;
                #pragma unroll
                for (int nt = 0; nt < 4; ++nt)
                    lds_b[prow*64 + swz(prow, nt*16 + l16)] = (__bf16)s[mt][nt][r];
            }
    }
    __syncthreads();   // p visible (and vt writes ordered for phase 3)

    // ---------------- phase 3: O = P @ V -----------------------------------
    {
        const int h = wave;
        bf16x8 bv[2][2];
        #pragma unroll
        for (int nv = 0; nv < 2; ++nv)
            #pragma unroll
            for (int kt = 0; kt < 2; ++kt) {
                int vr = h*32 + nv*16 + l16;
                bv[nv][kt] = *(bf16x8*)&lds_a[vr*64 + swz(vr, kt*32 + quad*8)];
            }
        bf16x8 ap[4][2];
        #pragma unroll
        for (int mt = 0; mt < 4; ++mt)
            #pragma unroll
            for (int kt = 0; kt < 2; ++kt) {
                int pr = (h << 6) + mt*16 + l16;
                ap[mt][kt] = *(bf16x8*)&lds_b[pr*64 + swz(pr, kt*32 + quad*8)];
            }
        __syncthreads();   // all p/vt fragments in regs before O overwrites lds_b

        f32x4 oacc[4][2];
        #pragma unroll
        for (int a = 0; a < 4; ++a)
            #pragma unroll
            for (int b = 0; b < 2; ++b) oacc[a][b] = (f32x4){0.f,0.f,0.f,0.f};
        #pragma unroll
        for (int mt = 0; mt < 4; ++mt)
            #pragma unroll
            for (int kt = 0; kt < 2; ++kt)
                #pragma unroll
                for (int nv = 0; nv < 2; ++nv)
                    oacc[mt][nv] = __builtin_amdgcn_mfma_f32_16x16x32_bf16(
                        ap[mt][kt], bv[nv][kt], oacc[mt][nv], 0, 0, 0);

        // write O into lds_b [64][128]
        #pragma unroll
        for (int mt = 0; mt < 4; ++mt)
            #pragma unroll
            for (int nv = 0; nv < 2; ++nv)
                #pragma unroll
                for (int r = 0; r < 4; ++r) {
                    int row = mt*16 + quad*4 + r;
                    lds_b[row*128 + swz(row, h*32 + nv*16 + l16)] = (__bf16)oacc[mt][nv][r];
                }
    }
    __syncthreads();   // O visible

    // ---------------- phase 4: out = O @ Wproj^T + b ------------------------
    #pragma unroll
    for (int ntl = 0; ntl < 2; ++ntl) {
        int o = (wave*2 + ntl) * 16 + l16;     // 0..127
        f32x4 acc[4];
        #pragma unroll
        for (int a = 0; a < 4; ++a) acc[a] = (f32x4){0.f,0.f,0.f,0.f};
        #pragma unroll
        for (int kt = 0; kt < 4; ++kt) {
            bf16x8 bf = *(const bf16x8*)(wproj + (size_t)o * CDIM + kt*32 + quad*8);
            #pragma unroll
            for (int mt = 0; mt < 4; ++mt) {
                int rr = mt*16 + l16;
                bf16x8 af = *(bf16x8*)&lds_b[rr*128 + swz(rr, kt*32 + quad*8)];
                acc[mt] = __builtin_amdgcn_mfma_f32_16x16x32_bf16(af, bf, acc[mt], 0, 0, 0);
            }
        }
        float pb = proj_b[o];
        #pragma unroll
        for (int mt = 0; mt < 4; ++mt)
            #pragma unroll
            for (int r = 0; r < 4; ++r) {
                int row = mt*16 + quad*4 + r;
                if (row < NTOK)
                    out[((size_t)w * NTOK + row) * CDIM + o] = acc[mt][r] + pb;
            }
    }
}

extern "C" void kernel_launch(void* const* d_in, const int* in_sizes, int n_in,
                              void* d_out, int out_size, void* d_ws, size_t ws_size,
                              hipStream_t stream) {
    const float* x          = (const float*)d_in[0];
    const float* mask       = (const float*)d_in[1];
    const float* qkv_w      = (const float*)d_in[2];
    const float* qkv_b      = (const float*)d_in[3];
    const float* proj_w     = (const float*)d_in[4];
    const float* proj_b     = (const float*)d_in[5];
    const float* bias_table = (const float*)d_in[6];
    const int*   rel_index  = (const int*)d_in[7];

    __bf16* wqkv  = (__bf16*)((char*)d_ws + WQKV_OFF);
    __bf16* wproj = (__bf16*)((char*)d_ws + WPROJ_OFF);
    float*  biasf = (float*)((char*)d_ws + BIASF_OFF);

    int nwb = in_sizes[0] / (NTOK * CDIM);   // 8192

    prep_kernel<<<192, 256, 0, stream>>>(qkv_w, proj_w, bias_table, rel_index,
                                         wqkv, wproj, biasf);
    winattn_kernel<<<nwb, 256, 0, stream>>>(x, mask, qkv_b, proj_b,
                                            wqkv, wproj, biasf, (float*)d_out);
}

// Round 2
// 543.688 us; speedup vs baseline: 1.1765x; 1.0137x over previous
//
#include <hip/hip_runtime.h>

typedef __bf16 bf16x8 __attribute__((ext_vector_type(8)));
typedef __bf16 bf16x4 __attribute__((ext_vector_type(4)));
typedef float  f32x4  __attribute__((ext_vector_type(4)));

#define NTOK  49
#define CDIM  128
#define LOG2E 1.4426950408889634f
#define QK2   (0.17677669529663687f * LOG2E)   // 1/sqrt(32) * log2(e)

// workspace offsets (bytes)
#define WQKV_OFF  0          // 384*128 bf16 = 98304
#define WPROJ_OFF 98304      // 128*128 bf16 = 32768
#define BIASB_OFF 131072     // [4][64][64] bf16 (log2e-scaled bias) = 32768
#define MASKB_OFF 163840     // [64][64][64] bf16 (log2e-scaled mask; j>=49 -> -1e30) = 524288

// Uniform LDS XOR swizzle on 8-element (16 B) granules within 64-col groups.
// All vector accesses (bf16x4 at col%8 in {0,4}; bf16x8 at col%8==0) stay
// inside one granule, so the swizzle is a pure bank permutation.
__device__ __forceinline__ int swz(int row, int col) {
    return (col & ~63) | ((((col >> 3) ^ row) & 7) << 3) | (col & 7);
}

__global__ void prep_kernel(const float* __restrict__ qkv_w,
                            const float* __restrict__ proj_w,
                            const float* __restrict__ bias_table,
                            const int*   __restrict__ rel_index,
                            const float* __restrict__ mask,
                            __bf16* __restrict__ wqkv,
                            __bf16* __restrict__ wproj,
                            __bf16* __restrict__ biasb,
                            __bf16* __restrict__ maskb) {
    int t = blockIdx.x * 256 + threadIdx.x;      // 0..65535 (256 blocks)
    if (t < 384 * 128) wqkv[t]  = (__bf16)qkv_w[t];
    if (t < 128 * 128) wproj[t] = (__bf16)proj_w[t];
    if (t < 4096) {                               // biasb[h][i][j], 4 j per thread
        int base = t * 4;
        int h = base >> 12, i = (base >> 6) & 63, j0 = base & 63;
        bf16x4 v;
        #pragma unroll
        for (int r = 0; r < 4; ++r) {
            int j = j0 + r;
            float f = 0.f;
            if (i < NTOK && j < NTOK) f = bias_table[rel_index[i*49 + j] * 4 + h] * LOG2E;
            v[r] = (__bf16)f;
        }
        *(bf16x4*)&biasb[base] = v;
    }
    {                                             // maskb[wm][i][j], 4 j per thread
        int base = t * 4;                         // < 262144 always
        int wm = base >> 12, i = (base >> 6) & 63, j0 = base & 63;
        bf16x4 v;
        #pragma unroll
        for (int r = 0; r < 4; ++r) {
            int j = j0 + r;
            float f;
            if (j >= NTOK)      f = -1e30f;       // masked key -> exp2 = 0
            else if (i < NTOK)  f = mask[wm*2401 + i*49 + j] * LOG2E;
            else                f = 0.f;
            v[r] = (__bf16)f;
        }
        *(bf16x4*)&maskb[base] = v;
    }
}

__launch_bounds__(256, 3)
__global__ void winattn_kernel(const float* __restrict__ x,
                               const float* __restrict__ qkv_b,
                               const float* __restrict__ proj_b,
                               const __bf16* __restrict__ wqkv,
                               const __bf16* __restrict__ wproj,
                               const __bf16* __restrict__ biasb,
                               const __bf16* __restrict__ maskb,
                               float* __restrict__ out) {
    // lds_a: x [64][128] -> vt [128][64]            (16 KB, aliased)
    // lds_b: q[64][0..127]|k[64][128..255] -> p[4][64][64] -> O[64][128] (32 KB, aliased)
    __shared__ __bf16 lds_a[64 * 128];
    __shared__ __bf16 lds_b[64 * 256];

    const int tid  = threadIdx.x;
    const int w    = blockIdx.x;
    const int wave = tid >> 6;
    const int lane = tid & 63;
    const int quad = lane >> 4;
    const int l16  = lane & 15;

    // ---------------- phase 0: x (fp32) -> lds_a (bf16), rows>=49 zeroed ----
    {
        int row = tid >> 2;           // 0..63
        int c0  = (tid & 3) * 32;     // 0,32,64,96
        __align__(16) __bf16 tmp[32];
        if (row < NTOK) {
            const float4* src = (const float4*)(x + ((size_t)w * NTOK + row) * CDIM + c0);
            #pragma unroll
            for (int i = 0; i < 8; ++i) {
                float4 f = src[i];
                tmp[i*4+0] = (__bf16)f.x; tmp[i*4+1] = (__bf16)f.y;
                tmp[i*4+2] = (__bf16)f.z; tmp[i*4+3] = (__bf16)f.w;
            }
        } else {
            #pragma unroll
            for (int i = 0; i < 32; ++i) tmp[i] = (__bf16)0.0f;
        }
        #pragma unroll
        for (int i = 0; i < 4; ++i)
            *(bf16x8*)&lds_a[row * 128 + swz(row, c0 + i*8)] = *(bf16x8*)&tmp[i*8];
    }
    __syncthreads();   // B1

    // ---------------- phase 1: qkv = x @ Wqkv^T + b ------------------------
    // q,k computed TRANSPOSED (mfma(W,x) -> D[chan][tok]): acc regs hold 4
    // contiguous chans at one tok -> vectorized bf16x4 stores into row-major
    // q_rm/k_rm[tok][chan]. v computed normal (mfma(x,Wv) -> D[tok][chan]):
    // 4 contiguous toks at one chan -> held in regs, stored to vt[chan][tok].
    bf16x4 vreg[2][4];
    #pragma unroll
    for (int half = 0; half < 2; ++half) {
        const int tq = half*4 + wave;        // q chan-tile 0..7
        const int tk = wave*2 + half;        // k chan-tile 0..7
        const int tv = half*4 + wave;        // v chan-tile 0..7
        f32x4 aq[4], ak[4], av[4];
        #pragma unroll
        for (int m = 0; m < 4; ++m) {
            aq[m] = (f32x4){0.f,0.f,0.f,0.f};
            ak[m] = (f32x4){0.f,0.f,0.f,0.f};
            av[m] = (f32x4){0.f,0.f,0.f,0.f};
        }
        #pragma unroll
        for (int kt = 0; kt < 4; ++kt) {
            bf16x8 xf[4];
            #pragma unroll
            for (int mt = 0; mt < 4; ++mt) {
                int rr = mt*16 + l16;
                xf[mt] = *(bf16x8*)&lds_a[rr * 128 + swz(rr, kt*32 + quad*8)];
            }
            bf16x8 wq = *(const bf16x8*)(wqkv + (size_t)(      tq*16 + l16) * CDIM + kt*32 + quad*8);
            bf16x8 wk = *(const bf16x8*)(wqkv + (size_t)(128 + tk*16 + l16) * CDIM + kt*32 + quad*8);
            bf16x8 wv = *(const bf16x8*)(wqkv + (size_t)(256 + tv*16 + l16) * CDIM + kt*32 + quad*8);
            #pragma unroll
            for (int mt = 0; mt < 4; ++mt) {
                aq[mt] = __builtin_amdgcn_mfma_f32_16x16x32_bf16(wq, xf[mt], aq[mt], 0, 0, 0); // D[chan][tok]
                ak[mt] = __builtin_amdgcn_mfma_f32_16x16x32_bf16(wk, xf[mt], ak[mt], 0, 0, 0); // D[chan][tok]
                av[mt] = __builtin_amdgcn_mfma_f32_16x16x32_bf16(xf[mt], wv, av[mt], 0, 0, 0); // D[tok][chan]
            }
        }
        float4 bq4 = *(const float4*)&qkv_b[      tq*16 + quad*4];
        float4 bk4 = *(const float4*)&qkv_b[128 + tk*16 + quad*4];
        float  bv1 = qkv_b[256 + tv*16 + l16];
        #pragma unroll
        for (int mt = 0; mt < 4; ++mt) {
            int row = mt*16 + l16;               // tok
            bf16x4 qv, kv, vv;
            #pragma unroll
            for (int r = 0; r < 4; ++r) {
                qv[r] = (__bf16)((aq[mt][r] + ((const float*)&bq4)[r]) * QK2);
                kv[r] = (__bf16)( ak[mt][r] + ((const float*)&bk4)[r]);
                vv[r] = (__bf16)( av[mt][r] + bv1);
            }
            *(bf16x4*)&lds_b[row*256 + swz(row,       tq*16 + quad*4)] = qv;
            *(bf16x4*)&lds_b[row*256 + swz(row, 128 + tk*16 + quad*4)] = kv;
            vreg[half][mt] = vv;
        }
    }
    __syncthreads();   // B2: x dead, q/k visible

    // v -> lds_a as vt[chan][tok]
    #pragma unroll
    for (int half = 0; half < 2; ++half) {
        int vc = (half*4 + wave)*16 + l16;       // chan 0..127
        #pragma unroll
        for (int mt = 0; mt < 4; ++mt)
            *(bf16x4*)&lds_a[vc * 64 + swz(vc, mt*16 + quad*4)] = vreg[half][mt];
    }

    // ---------------- phase 2: S^T = k q^T; softmax (in-register) ----------
    const int h = wave;
    float inv[4];
    {
        bf16x8 kf[4], qf[4];
        #pragma unroll
        for (int t = 0; t < 4; ++t) {
            int rr = t*16 + l16;
            kf[t] = *(bf16x8*)&lds_b[rr*256 + swz(rr, 128 + h*32 + quad*8)];
            qf[t] = *(bf16x8*)&lds_b[rr*256 + swz(rr,       h*32 + quad*8)];
        }
        __syncthreads();   // B3: all q/k reads in regs; vt visible; lds_b reusable

        f32x4 s2[4][4];    // [mtq][ntk]: D[ktok][qtok], lane = qtok
        #pragma unroll
        for (int mtq = 0; mtq < 4; ++mtq)
            #pragma unroll
            for (int ntk = 0; ntk < 4; ++ntk) {
                f32x4 z = (f32x4){0.f,0.f,0.f,0.f};
                s2[mtq][ntk] = __builtin_amdgcn_mfma_f32_16x16x32_bf16(kf[ntk], qf[mtq], z, 0, 0, 0);
            }

        const __bf16* bb = biasb + h * 4096;
        const __bf16* mb = maskb + (size_t)(w & 63) * 4096;
        #pragma unroll
        for (int mtq = 0; mtq < 4; ++mtq) {
            int i = mtq*16 + l16;                // qtok (lane-resident)
            float e[4][4], sum = 0.f;
            #pragma unroll
            for (int ntk = 0; ntk < 4; ++ntk) {
                int j0 = ntk*16 + quad*4;        // ktok base (reg-resident)
                bf16x4 b4 = *(const bf16x4*)&bb[i*64 + j0];
                bf16x4 m4 = *(const bf16x4*)&mb[i*64 + j0];
                #pragma unroll
                for (int r = 0; r < 4; ++r) {
                    float t = s2[mtq][ntk][r] + (float)b4[r] + (float)m4[r];
                    e[ntk][r] = __builtin_amdgcn_exp2f(t);   // no max-sub: |t| bounded
                    sum += e[ntk][r];
                }
            }
            sum += __shfl_xor(sum, 16, 64);
            sum += __shfl_xor(sum, 32, 64);
            inv[mtq] = __builtin_amdgcn_rcpf(sum);           // normalization deferred
            // store unnormalized P (wave-private region p[h])
            #pragma unroll
            for (int ntk = 0; ntk < 4; ++ntk) {
                bf16x4 pv;
                #pragma unroll
                for (int r = 0; r < 4; ++r) pv[r] = (__bf16)e[ntk][r];
                *(bf16x4*)&lds_b[h*4096 + i*64 + swz(i, ntk*16 + quad*4)] = pv;
            }
        }
    }

    // ---------------- phase 3: O^T = V^T P^T -------------------------------
    {
        bf16x8 vf[2][2];
        #pragma unroll
        for (int nv = 0; nv < 2; ++nv)
            #pragma unroll
            for (int kt = 0; kt < 2; ++kt) {
                int vr = h*32 + nv*16 + l16;     // chan
                vf[nv][kt] = *(bf16x8*)&lds_a[vr*64 + swz(vr, kt*32 + quad*8)];
            }
        bf16x8 pf[4][2];
        #pragma unroll
        for (int mtq = 0; mtq < 4; ++mtq)
            #pragma unroll
            for (int kt = 0; kt < 2; ++kt) {
                int pr = mtq*16 + l16;           // qtok (same-wave P read)
                pf[mtq][kt] = *(bf16x8*)&lds_b[h*4096 + pr*64 + swz(pr, kt*32 + quad*8)];
            }
        __syncthreads();   // B4: all P/vt fragment reads done; lds_b reusable

        f32x4 oacc[2][4];  // [nv][mtq]: D[chan][qtok], lane = qtok
        #pragma unroll
        for (int a = 0; a < 2; ++a)
            #pragma unroll
            for (int b = 0; b < 4; ++b) oacc[a][b] = (f32x4){0.f,0.f,0.f,0.f};
        #pragma unroll
        for (int mtq = 0; mtq < 4; ++mtq)
            #pragma unroll
            for (int kt = 0; kt < 2; ++kt)
                #pragma unroll
                for (int nv = 0; nv < 2; ++nv)
                    oacc[nv][mtq] = __builtin_amdgcn_mfma_f32_16x16x32_bf16(
                        vf[nv][kt], pf[mtq][kt], oacc[nv][mtq], 0, 0, 0);

        // normalize with lane-resident inv, store O_rm[qtok][chan] into lds_b
        #pragma unroll
        for (int nv = 0; nv < 2; ++nv)
            #pragma unroll
            for (int mtq = 0; mtq < 4; ++mtq) {
                int row = mtq*16 + l16;          // qtok
                bf16x4 ov;
                #pragma unroll
                for (int r = 0; r < 4; ++r) ov[r] = (__bf16)(oacc[nv][mtq][r] * inv[mtq]);
                *(bf16x4*)&lds_b[row*128 + swz(row, h*32 + nv*16 + quad*4)] = ov;
            }
    }
    __syncthreads();   // B5: O visible

    // ---------------- phase 4: out^T = Wproj O^T ---------------------------
    #pragma unroll
    for (int ntl = 0; ntl < 2; ++ntl) {
        int oc = (wave*2 + ntl) * 16;            // out-chan tile base
        f32x4 acc[4];
        #pragma unroll
        for (int a = 0; a < 4; ++a) acc[a] = (f32x4){0.f,0.f,0.f,0.f};
        #pragma unroll
        for (int kt = 0; kt < 4; ++kt) {
            bf16x8 wf = *(const bf16x8*)(wproj + (size_t)(oc + l16) * CDIM + kt*32 + quad*8);
            #pragma unroll
            for (int mt = 0; mt < 4; ++mt) {
                int rr = mt*16 + l16;
                bf16x8 of = *(bf16x8*)&lds_b[rr*128 + swz(rr, kt*32 + quad*8)];
                acc[mt] = __builtin_amdgcn_mfma_f32_16x16x32_bf16(wf, of, acc[mt], 0, 0, 0); // D[ochan][tok]
            }
        }
        float4 pb4 = *(const float4*)&proj_b[oc + quad*4];
        #pragma unroll
        for (int mt = 0; mt < 4; ++mt) {
            int tok = mt*16 + l16;
            if (tok < NTOK) {
                float4 o4;
                o4.x = acc[mt][0] + pb4.x;
                o4.y = acc[mt][1] + pb4.y;
                o4.z = acc[mt][2] + pb4.z;
                o4.w = acc[mt][3] + pb4.w;
                *(float4*)&out[((size_t)w * NTOK + tok) * CDIM + oc + quad*4] = o4;
            }
        }
    }
}

extern "C" void kernel_launch(void* const* d_in, const int* in_sizes, int n_in,
                              void* d_out, int out_size, void* d_ws, size_t ws_size,
                              hipStream_t stream) {
    const float* x          = (const float*)d_in[0];
    const float* mask       = (const float*)d_in[1];
    const float* qkv_w      = (const float*)d_in[2];
    const float* qkv_b      = (const float*)d_in[3];
    const float* proj_w     = (const float*)d_in[4];
    const float* proj_b     = (const float*)d_in[5];
    const float* bias_table = (const float*)d_in[6];
    const int*   rel_index  = (const int*)d_in[7];

    __bf16* wqkv  = (__bf16*)((char*)d_ws + WQKV_OFF);
    __bf16* wproj = (__bf16*)((char*)d_ws + WPROJ_OFF);
    __bf16* biasb = (__bf16*)((char*)d_ws + BIASB_OFF);
    __bf16* maskb = (__bf16*)((char*)d_ws + MASKB_OFF);

    int nwb = in_sizes[0] / (NTOK * CDIM);   // 8192

    prep_kernel<<<256, 256, 0, stream>>>(qkv_w, proj_w, bias_table, rel_index, mask,
                                         wqkv, wproj, biasb, maskb);
    winattn_kernel<<<nwb, 256, 0, stream>>>(x, qkv_b, proj_b,
                                            wqkv, wproj, biasb, maskb, (float*)d_out);
}